// Round 4
// baseline (139.552 us; speedup 1.0000x reference)
//
#include <hip/hip_runtime.h>

// ChannelAttention fused kernel for MI355X (gfx950), round 8.
// B=4, L=16384, C=128, H=8, hd=16. Tokens M = 65536.
//
// R8: intra-wave 2-tile software pipeline to break phase-locked stalls.
// R4/R6/R7 post-mortem: dur ~60us invariant across occupancy 26->36% and
// barriers 4->1; VALUBusy pinned ~35%, no pipe saturated. Diagnosis: all
// resident blocks run the identical phase sequence in lockstep, so memory
// stalls (x HBM/L3 latency, weight L2 latency, LDS RAW, post-barrier
// bubbles) hit every wave simultaneously and never overlap compute.
// Fix: each block processes 2 consecutive 32-token tiles (grid 1024 =
// exactly one resident generation of 4 blocks/CU):
//   - T1's x loads issue in two 8x dwordx4 batches under T0's exp bursts
//     (issue-early / pack-late), hiding HBM latency under TRANS work.
//   - Post-B1 bubble filled with T1 qkv-MFMA + T0 projection (independent).
//   - Weight loads for T1 hit hot L2; acc/afr registers reused across tiles
//     (only +32 VGPR transient for the x prefetch).
//   - us_f stays wave-private (R7 head-aligned decomposition, 0 barriers in
//     qkv path); us_o single-buffered, 3 barriers/block = 1.5/tile.
// LDS unchanged 24832+8704 = 33536 B -> 4 blocks/CU. Math path bit-identical
// to R7 (fp32 LDS, bf16 MFMA operands, exp2 softmax) -> absmax must match.

typedef __attribute__((ext_vector_type(8))) short bf16x8;
typedef __attribute__((ext_vector_type(4))) float f32x4;
typedef __attribute__((ext_vector_type(4))) unsigned int u32x4;

#define TILE_M 32
#define HALF_M 16
#define QKV_STRIDE_F 388   // fp32 elems per token row (>=384; %8==4 -> 16B aligned rows, spread banks)
#define O_STRIDE 136       // bf16 elems per o row

__device__ __forceinline__ unsigned short f2bf(float f) {
    unsigned int u = __builtin_bit_cast(unsigned int, f);
    u += 0x8000u;                      // round half up (cheap, <=0.5 ulp + tie bias)
    return (unsigned short)(u >> 16);
}
// pack two floats -> packed bf16x2 (lo in low short) in 3 VALU ops
__device__ __forceinline__ unsigned int pkbf(float lo, float hi) {
    unsigned int a = __builtin_bit_cast(unsigned int, lo) + 0x8000u;
    unsigned int b = __builtin_bit_cast(unsigned int, hi) + 0x8000u;
    return __builtin_amdgcn_perm(b, a, 0x07060302u);  // {hi16(b),hi16(a)}
}

__global__ void prep_weights(const float* __restrict__ wqkv,
                             const float* __restrict__ wproj,
                             unsigned short* __restrict__ wqkvT,
                             unsigned short* __restrict__ wprojT) {
    int idx = blockIdx.x * 256 + threadIdx.x;
    if (idx < 384 * 128) {               // wqkvT[n][k] = bf16(wqkv[k][n])
        int n = idx >> 7, k = idx & 127;
        wqkvT[idx] = f2bf(wqkv[k * 384 + n]);
    }
    if (idx < 128 * 128) {               // wprojT[n][k] = bf16(wproj[k][n])
        int n = idx >> 7, k = idx & 127;
        wprojT[idx] = f2bf(wproj[k * 128 + n]);
    }
}

__global__ __launch_bounds__(256, 4) void fused_channel_attn(
    const float* __restrict__ x,
    const unsigned short* __restrict__ wqkvT,
    const float* __restrict__ bqkv,
    const unsigned short* __restrict__ wprojT,
    const float* __restrict__ bproj,
    float* __restrict__ out)
{
    __shared__ __align__(16) float us_f[HALF_M * QKV_STRIDE_F];        // 24832 B, half-tile qkv fp32 (wave-private columns)
    __shared__ __align__(16) unsigned short us_o[TILE_M * O_STRIDE];   // 8704 B, full-tile o bf16

    const int tid  = threadIdx.x;
    const int lane = tid & 63;
    const int wave = tid >> 6;
    const int col  = lane & 15;   // MFMA C/D col == A row (m) == B col (n)
    const int quad = lane >> 4;
    const long tok0 = (long)blockIdx.x * 2 * TILE_M;
    const long tok1 = tok0 + TILE_M;

    // head-aligned n-tiles: wave w produces q,k,v channel tiles of heads 2w, 2w+1
    int ntile[6];
    ntile[0] = 2 * wave;      ntile[1] = 2 * wave + 1;
    ntile[2] = 8 + 2 * wave;  ntile[3] = 9 + 2 * wave;
    ntile[4] = 16 + 2 * wave; ntile[5] = 17 + 2 * wave;

    float bqv[6];                 // qkv bias, held whole kernel
#pragma unroll
    for (int j = 0; j < 6; ++j) bqv[j] = bqkv[ntile[j] * 16 + col];

    bf16x8 afr[2][4];             // A-fragments, reused T0 then T1
    f32x4  acc[2][6];             // qkv accumulators, reused T0 then T1

    // ---- stage A: x fragments, load+pack fused per (m,ks)
    auto load_pack_x = [&](long bt) {
#pragma unroll
        for (int m = 0; m < 2; ++m) {
            const float* xrow = x + (bt + m * 16 + col) * 128;
#pragma unroll
            for (int ks = 0; ks < 4; ++ks) {
                const float4* p = (const float4*)(xrow + ks * 32 + quad * 8);
                float4 f0 = p[0], f1 = p[1];
                u32x4 a = {pkbf(f0.x, f0.y), pkbf(f0.z, f0.w),
                           pkbf(f1.x, f1.y), pkbf(f1.z, f1.w)};
                afr[m][ks] = __builtin_bit_cast(bf16x8, a);
            }
        }
    };

    // qkv = x @ WqkvT + b for both m-tiles of the current tile
    auto mfma_qkv = [&]() {
#pragma unroll
        for (int j = 0; j < 6; ++j) {
            acc[0][j] = (f32x4){bqv[j], bqv[j], bqv[j], bqv[j]};
            acc[1][j] = (f32x4){bqv[j], bqv[j], bqv[j], bqv[j]};
        }
#pragma unroll
        for (int ks = 0; ks < 4; ++ks) {
            bf16x8 bfr[6];
#pragma unroll
            for (int j = 0; j < 6; ++j)
                bfr[j] = *(const bf16x8*)&wqkvT[(ntile[j] * 16 + col) * 128 + ks * 32 + quad * 8];
#pragma unroll
            for (int j = 0; j < 6; ++j) {
                acc[0][j] = __builtin_amdgcn_mfma_f32_16x16x32_bf16(afr[0][ks], bfr[j], acc[0][j], 0, 0, 0);
                acc[1][j] = __builtin_amdgcn_mfma_f32_16x16x32_bf16(afr[1][ks], bfr[j], acc[1][j], 0, 0, 0);
            }
        }
    };

    // ---- stage B lane roles: (token, head-bit, i-half) within the wave
    const int t    = lane & 15;
    const int hbit = (lane >> 4) & 1;
    const int ih   = lane >> 5;
    const int h    = 2 * wave + hbit;           // head owned by this lane
    const float* qkvrow = us_f + t * QKV_STRIDE_F + h * 16;
    const float sl2e = 0.08838834764831845f * 1.44269504088896340f; // scale*log2(e)

    // write one 16-token half of this wave's qkv columns -> LDS fp32 [tok][ch]
    auto write_half = [&](int m) {
#pragma unroll
        for (int j = 0; j < 6; ++j)
#pragma unroll
            for (int r = 0; r < 4; ++r)
                us_f[(quad * 4 + r) * QKV_STRIDE_F + ntile[j] * 16 + col] = acc[m][j][r];
    };

    float4 qv4[2], kv4[4], vv4[4];   // 10 ds_read_b128 per half
    auto read_half = [&]() {
        qv4[0] = ((const float4*)(qkvrow + ih * 8))[0];
        qv4[1] = ((const float4*)(qkvrow + ih * 8))[1];
#pragma unroll
        for (int c = 0; c < 4; ++c) {
            kv4[c] = ((const float4*)(qkvrow + 128))[c];
            vv4[c] = ((const float4*)(qkvrow + 256))[c];
        }
    };

    auto attn_half = [&](int mhalf) {
        float qv[8], kf[16], vf[16];
#pragma unroll
        for (int c = 0; c < 2; ++c) {
            qv[4*c] = qv4[c].x; qv[4*c+1] = qv4[c].y; qv[4*c+2] = qv4[c].z; qv[4*c+3] = qv4[c].w;
        }
#pragma unroll
        for (int c = 0; c < 4; ++c) {
            kf[4*c] = kv4[c].x; kf[4*c+1] = kv4[c].y; kf[4*c+2] = kv4[c].z; kf[4*c+3] = kv4[c].w;
            vf[4*c] = vv4[c].x; vf[4*c+1] = vv4[c].y; vf[4*c+2] = vv4[c].z; vf[4*c+3] = vv4[c].w;
        }
        float ov[8];
#pragma unroll
        for (int i = 0; i < 8; ++i) {
            float qs = qv[i] * sl2e;
            float den = 0.f, num = 0.f;
#pragma unroll
            for (int j = 0; j < 16; ++j) {
                float e = __builtin_amdgcn_exp2f(qs * kf[j]);
                den += e;
                num = fmaf(e, vf[j], num);
            }
            ov[i] = num * __builtin_amdgcn_rcpf(den);
        }
        u32x4 o0 = {pkbf(ov[0], ov[1]), pkbf(ov[2], ov[3]),
                    pkbf(ov[4], ov[5]), pkbf(ov[6], ov[7])};
        *(u32x4*)&us_o[(mhalf * 16 + t) * O_STRIDE + h * 16 + ih * 8] = o0;  // b128, A-layout
    };

    // out = o @ Wproj + b for one tile. Wave: 2 n-tiles x 2 m-tiles.
    auto stage_c = [&](long bt) {
        const int nb2 = wave * 2;
#pragma unroll
        for (int m = 0; m < 2; ++m) {
            bf16x8 af[4];
#pragma unroll
            for (int ks = 0; ks < 4; ++ks)
                af[ks] = *(const bf16x8*)&us_o[(m * 16 + col) * O_STRIDE + ks * 32 + quad * 8];
            f32x4 acc2[2];
#pragma unroll
            for (int n = 0; n < 2; ++n) {
                float b = bproj[(nb2 + n) * 16 + col];
                acc2[n] = (f32x4){b, b, b, b};
            }
#pragma unroll
            for (int ks = 0; ks < 4; ++ks) {
                bf16x8 bb[2];
#pragma unroll
                for (int n = 0; n < 2; ++n)
                    bb[n] = *(const bf16x8*)&wprojT[((nb2 + n) * 16 + col) * 128 + ks * 32 + quad * 8];
#pragma unroll
                for (int n = 0; n < 2; ++n)
                    acc2[n] = __builtin_amdgcn_mfma_f32_16x16x32_bf16(af[ks], bb[n], acc2[n], 0, 0, 0);
            }
#pragma unroll
            for (int n = 0; n < 2; ++n)
#pragma unroll
                for (int r = 0; r < 4; ++r) {
                    long tt = bt + m * 16 + quad * 4 + r;
                    out[tt * 128 + (nb2 + n) * 16 + col] = acc2[n][r];
                }
        }
    };

    // ================= 2-tile pipeline =================
    // --- T0 front half
    load_pack_x(tok0);
    mfma_qkv();                    // acc = qkv(T0)

    write_half(0);                 // 24 ds_write_b32 (wave-private)
    read_half();                   // RAW same wave: in-order DS

    // prefetch T1 x, m=0 batch (8 dwordx4) - lands under the exp burst below
    float4 xp[8];
    {
        const float* xrow = x + (tok1 + col) * 128;
#pragma unroll
        for (int ks = 0; ks < 4; ++ks) {
            const float4* p = (const float4*)(xrow + ks * 32 + quad * 8);
            xp[2*ks] = p[0]; xp[2*ks+1] = p[1];
        }
    }
    write_half(1);                 // anti-dep on reads: program order keeps safe
    attn_half(0);                  // exp burst hides xp batch-0 latency

    // pack batch-0 -> afr[0] (vmcnt wait lands here, loads long done)
#pragma unroll
    for (int ks = 0; ks < 4; ++ks) {
        float4 f0 = xp[2*ks], f1 = xp[2*ks+1];
        u32x4 a = {pkbf(f0.x, f0.y), pkbf(f0.z, f0.w),
                   pkbf(f1.x, f1.y), pkbf(f1.z, f1.w)};
        afr[0][ks] = __builtin_bit_cast(bf16x8, a);
    }
    // prefetch T1 x, m=1 batch - lands under the second exp burst
    {
        const float* xrow = x + (tok1 + 16 + col) * 128;
#pragma unroll
        for (int ks = 0; ks < 4; ++ks) {
            const float4* p = (const float4*)(xrow + ks * 32 + quad * 8);
            xp[2*ks] = p[0]; xp[2*ks+1] = p[1];
        }
    }
    read_half();                   // half-1 reads (RAW on write_half(1), same wave)
    attn_half(1);                  // -> us_o(T0) complete for this wave
#pragma unroll
    for (int ks = 0; ks < 4; ++ks) {
        float4 f0 = xp[2*ks], f1 = xp[2*ks+1];
        u32x4 a = {pkbf(f0.x, f0.y), pkbf(f0.z, f0.w),
                   pkbf(f1.x, f1.y), pkbf(f1.z, f1.w)};
        afr[1][ks] = __builtin_bit_cast(bf16x8, a);
    }

    __syncthreads();               // B1: us_o(T0) visible to all waves

    // --- post-barrier bubble filled: T1 qkv MFMA + T0 projection (independent)
    mfma_qkv();                    // acc = qkv(T1), weights now L2-hot
    stage_c(tok0);                 // reads us_o(T0), writes out rows tok0..+31

    __syncthreads();               // B2: all us_o(T0) reads done before overwrite

    // --- T1 back half (same wave-private qkv pipeline)
    write_half(0);
    read_half();
    write_half(1);
    attn_half(0);
    read_half();
    attn_half(1);

    __syncthreads();               // B3: us_o(T1) visible
    stage_c(tok1);
}

extern "C" void kernel_launch(void* const* d_in, const int* in_sizes, int n_in,
                              void* d_out, int out_size, void* d_ws, size_t ws_size,
                              hipStream_t stream) {
    const float* x     = (const float*)d_in[0];
    const float* wqkv  = (const float*)d_in[1];
    const float* bqkv  = (const float*)d_in[2];
    const float* wproj = (const float*)d_in[3];
    const float* bproj = (const float*)d_in[4];
    float* out = (float*)d_out;

    unsigned short* wqkvT  = (unsigned short*)d_ws;    // 384*128 bf16
    unsigned short* wprojT = wqkvT + 384 * 128;        // 128*128 bf16

    prep_weights<<<192, 256, 0, stream>>>(wqkv, wproj, wqkvT, wprojT);

    const int tokens = in_sizes[0] / 128;              // 65536
    fused_channel_attn<<<tokens / (2 * TILE_M), 256, 0, stream>>>(
        x, wqkvT, bqkv, wprojT, bproj, out);
}